// Round 1
// baseline (17.033 us; speedup 1.0000x reference)
//
#include <hip/hip_runtime.h>

// Problem geometry (fixed by reference):
//   preds : (B=2, T=8, E=16, H=128, W=256) f32
//   target: (B=2, T=8, 1,    H=128, W=256) f32
//   output: scalar f32
#define HW    32768   // 128*256
#define T_DIM 8
#define E_DIM 16
#define NPOS  65536   // B * HW
#define BLK   256
#define NBLK  (NPOS / BLK)   // 256

__device__ __forceinline__ float block_reduce_256(float v, float* lds) {
    // wave64 shuffle reduce
#pragma unroll
    for (int off = 32; off; off >>= 1)
        v += __shfl_down(v, off, 64);
    int lane = threadIdx.x & 63;
    int wid  = threadIdx.x >> 6;
    if (lane == 0) lds[wid] = v;
    __syncthreads();
    return lds[0] + lds[1] + lds[2] + lds[3];
}

__global__ __launch_bounds__(BLK) void crps_partial(const float* __restrict__ preds,
                                                    const float* __restrict__ target,
                                                    float* __restrict__ partials) {
    const int n  = blockIdx.x * BLK + threadIdx.x;  // 0..65535
    const int b  = n >> 15;                          // 0..1
    const int hw = n & (HW - 1);

    const float* pb = preds  + (size_t)b * T_DIM * E_DIM * HW + hw;
    const float* tb = target + (size_t)b * T_DIM * HW + hw;

    float acc  = 0.f;   // sum over t of (term1 - term2)
    float tacc = 0.f;   // sum over t>=1, e of |p[t]-p[t-1]|
    float prev[E_DIM];

#pragma unroll
    for (int t = 0; t < T_DIM; ++t) {
        float cur[E_DIM];
#pragma unroll
        for (int e = 0; e < E_DIM; ++e)
            cur[e] = pb[((size_t)t * E_DIM + e) * HW];
        const float tgt = tb[(size_t)t * HW];

        // term1: sum_e |p_e - tgt|
        float t1 = 0.f;
#pragma unroll
        for (int e = 0; e < E_DIM; ++e)
            t1 += fabsf(cur[e] - tgt);

        // term2 core: S = sum_{i<j} |p_i - p_j|
        float s = 0.f;
#pragma unroll
        for (int i = 0; i < E_DIM; ++i)
#pragma unroll
            for (int j = i + 1; j < E_DIM; ++j)
                s += fabsf(cur[i] - cur[j]);

        acc += t1 * (1.f / 16.f) - s * (1.f / 256.f);

        if (t > 0) {
#pragma unroll
            for (int e = 0; e < E_DIM; ++e)
                tacc += fabsf(cur[e] - prev[e]);
        }
#pragma unroll
        for (int e = 0; e < E_DIM; ++e)
            prev[e] = cur[e];
    }

    // crps contribution of this (b,hw): mean over t (/8) + 0.1 * mean over (7*16)
    float v = acc * (1.f / 8.f) + tacc * (0.1f / 112.f);

    __shared__ float lds[4];
    float bsum = block_reduce_256(v, lds);
    if (threadIdx.x == 0)
        partials[blockIdx.x] = bsum;
}

__global__ __launch_bounds__(BLK) void crps_final(const float* __restrict__ partials,
                                                  float* __restrict__ out) {
    float v = partials[threadIdx.x];   // exactly 256 partials
    __shared__ float lds[4];
    float total = block_reduce_256(v, lds);
    if (threadIdx.x == 0)
        out[0] = total * (1.f / (float)NPOS);
}

extern "C" void kernel_launch(void* const* d_in, const int* in_sizes, int n_in,
                              void* d_out, int out_size, void* d_ws, size_t ws_size,
                              hipStream_t stream) {
    const float* preds  = (const float*)d_in[0];
    const float* target = (const float*)d_in[1];
    float* out      = (float*)d_out;
    float* partials = (float*)d_ws;   // 256 floats = 1 KB scratch

    crps_partial<<<NBLK, BLK, 0, stream>>>(preds, target, partials);
    crps_final<<<1, BLK, 0, stream>>>(partials, out);
}

// Round 2
// 13.680 us; speedup vs baseline: 1.2451x; 1.2451x over previous
//
#include <hip/hip_runtime.h>

// Problem geometry (fixed by reference):
//   preds : (B=2, T=8, E=16, H=128, W=256) f32
//   target: (B=2, T=8, 1,    H=128, W=256) f32
//   output: scalar f32
#define HW    32768   // 128*256
#define T_DIM 8
#define E_DIM 16
#define NPOS  65536   // B * HW
#define BLK   256
#define KPAIR 4                         // t-pairs per (b,hw)
#define NTHREADS (2 * KPAIR * HW)       // 262144
#define NBLK  (NTHREADS / BLK)          // 1024

__device__ __forceinline__ float block_reduce_256(float v, float* lds) {
#pragma unroll
    for (int off = 32; off; off >>= 1)
        v += __shfl_down(v, off, 64);
    int lane = threadIdx.x & 63;
    int wid  = threadIdx.x >> 6;
    if (lane == 0) lds[wid] = v;
    __syncthreads();
    return lds[0] + lds[1] + lds[2] + lds[3];
}

// term1/16 - term2core/256 for one (b,t,hw): p[16] vs tgt
__device__ __forceinline__ float crps_term(const float* p, float tgt) {
    float t1 = 0.f;
#pragma unroll
    for (int e = 0; e < E_DIM; ++e)
        t1 += fabsf(p[e] - tgt);
    float s = 0.f;
#pragma unroll
    for (int i = 0; i < E_DIM; ++i)
#pragma unroll
        for (int j = i + 1; j < E_DIM; ++j)
            s += fabsf(p[i] - p[j]);
    return t1 * (1.f / 16.f) - s * (1.f / 256.f);
}

__global__ __launch_bounds__(BLK) void crps_partial(const float* __restrict__ preds,
                                                    const float* __restrict__ target,
                                                    float* __restrict__ partials) {
    const int n  = blockIdx.x * BLK + threadIdx.x;   // 0..NTHREADS-1
    const int hw = n & (HW - 1);
    const int k  = (n >> 15) & (KPAIR - 1);          // t-pair index 0..3
    const int b  = n >> 17;                          // 0..1
    const int t0 = 2 * k;

    const float* pb = preds  + (size_t)b * T_DIM * E_DIM * HW + hw;
    const float* tb = target + (size_t)b * T_DIM * HW + hw;

    float cur0[E_DIM], cur1[E_DIM];
#pragma unroll
    for (int e = 0; e < E_DIM; ++e)
        cur0[e] = pb[((size_t)(t0 * E_DIM) + e) * HW];
#pragma unroll
    for (int e = 0; e < E_DIM; ++e)
        cur1[e] = pb[((size_t)((t0 + 1) * E_DIM) + e) * HW];

    const float tgt0 = tb[(size_t)t0 * HW];
    const float tgt1 = tb[(size_t)(t0 + 1) * HW];

    // temporal: boundary transition (t0-1 -> t0) for k>0, loaded then dropped
    float tacc = 0.f;
    if (k > 0) {
#pragma unroll
        for (int e = 0; e < E_DIM; ++e) {
            float pv = pb[((size_t)((t0 - 1) * E_DIM) + e) * HW];
            tacc += fabsf(cur0[e] - pv);
        }
    }
    // within-pair transition (t0 -> t0+1)
#pragma unroll
    for (int e = 0; e < E_DIM; ++e)
        tacc += fabsf(cur1[e] - cur0[e]);

    float acc = crps_term(cur0, tgt0) + crps_term(cur1, tgt1);

    // per-(b,hw) scaling: crps terms averaged over 8 t; temporal over 112
    float v = acc * (1.f / 8.f) + tacc * (0.1f / 112.f);

    __shared__ float lds[4];
    float bsum = block_reduce_256(v, lds);
    if (threadIdx.x == 0)
        partials[blockIdx.x] = bsum;
}

__global__ __launch_bounds__(BLK) void crps_final(const float* __restrict__ partials,
                                                  float* __restrict__ out) {
    float v = 0.f;
#pragma unroll
    for (int i = 0; i < NBLK / BLK; ++i)            // 4 partials per thread
        v += partials[i * BLK + threadIdx.x];
    __shared__ float lds[4];
    float total = block_reduce_256(v, lds);
    if (threadIdx.x == 0)
        out[0] = total * (1.f / (float)NPOS);
}

extern "C" void kernel_launch(void* const* d_in, const int* in_sizes, int n_in,
                              void* d_out, int out_size, void* d_ws, size_t ws_size,
                              hipStream_t stream) {
    const float* preds  = (const float*)d_in[0];
    const float* target = (const float*)d_in[1];
    float* out      = (float*)d_out;
    float* partials = (float*)d_ws;   // 1024 floats = 4 KB scratch

    crps_partial<<<NBLK, BLK, 0, stream>>>(preds, target, partials);
    crps_final<<<1, BLK, 0, stream>>>(partials, out);
}